// Round 11
// baseline (180.921 us; speedup 1.0000x reference)
//
#include <hip/hip_runtime.h>

#define NUM_LAYERS 1000
#define DIM 10
#define STRIDE 112           // floats per affine slot (10x11 = 110, padded to 112)
#define LPB128 128           // padded layers per compose block
#define REAL125 125          // real layers per compose block (8 * 125 = 1000)
#define NCH8 8               // chunk count
#define WQ4 320              // float4 per wave in apply (64 lanes * 5)
#define TILE_Q4 1280         // float4 per block (4 waves)

// Direct global->LDS DMA, 16 B per lane. LDS dest is wave-uniform base +
// lane*16 (m104/m108); global src is per-lane. Counter: vmcnt.
__device__ inline void gload_lds16(const void* g, void* l) {
    __builtin_amdgcn_global_load_lds(
        (const __attribute__((address_space(1))) void*)g,
        (__attribute__((address_space(3))) void*)l, 16, 0, 0);
}

// Affine stored col-major in a slot: slot[j*10 + r] = M[r][j] for j<10,
// slot[100 + r] = c[r]. Compose dst = g(f(.)): col_j(dst) = M_g * col_j(f)
// (+ c_g when j==10). Lane j (0..10) owns column j.
// NOTE: no __restrict__ — the apply-side fold aliases src/dst buffer regions
// (disjoint slot ranges, but same underlying array).
__device__ inline void compose_one(const float* src, float* dst, int c, int lane) {
    const float* F = src + (size_t)(2 * c) * STRIDE;
    const float* G = src + (size_t)(2 * c + 1) * STRIDE;
    float colf[DIM], o[DIM];
    #pragma unroll
    for (int r = 0; r < DIM; ++r) colf[r] = F[lane * DIM + r];
    #pragma unroll
    for (int r = 0; r < DIM; ++r) {
        float acc = (lane == DIM) ? G[100 + r] : 0.f;
        #pragma unroll
        for (int k = 0; k < DIM; ++k)
            acc += G[k * DIM + r] * colf[k];
        o[r] = acc;
    }
    float* D = dst + (size_t)c * STRIDE;
    #pragma unroll
    for (int r = 0; r < DIM; ++r) D[lane * DIM + r] = o[r];
}

// ---------------------------------------------------------------------------
// K1: block b folds layers [125b, 125b+125) (identity-padded to 128) via the
// proven ping-pong LDS tree: 7 levels, 64->32->...->1 composes. 16 waves,
// wave per compose. Writes chunk affine b col-major to wsout slot b.
// ---------------------------------------------------------------------------
__global__ __launch_bounds__(1024) void compose128(const float* __restrict__ Ws,
                                                   const float* __restrict__ bs,
                                                   float* __restrict__ wsout) {
    __shared__ float A[LPB128 * STRIDE];   // 57.3 KB
    __shared__ float B[64 * STRIDE];       // 28.7 KB
    const int tid = threadIdx.x, blk = blockIdx.x;

    for (int e = tid; e < LPB128 * 100; e += 1024) {
        int ll = e / 100, rem = e % 100;      // rem = r*10 + k
        int r = rem / 10, k = rem % 10;
        float v = (ll < REAL125) ? Ws[(size_t)(blk * REAL125 + ll) * 100 + rem]
                                 : (r == k ? 1.f : 0.f);
        A[ll * STRIDE + k * DIM + r] = v;
    }
    for (int e = tid; e < LPB128 * DIM; e += 1024) {
        int ll = e / DIM, r = e % DIM;
        float v = (ll < REAL125) ? bs[(size_t)(blk * REAL125 + ll) * DIM + r] : 0.f;
        A[ll * STRIDE + 100 + r] = v;
    }

    const int wave = tid >> 6, lane = tid & 63;
    const float* src = A;
    float* dst = B;
    for (int n = 64; n >= 1; n >>= 1) {        // 7 levels
        __syncthreads();
        if (lane <= DIM)
            for (int c = wave; c < n; c += 16)
                compose_one(src, dst, c, lane);
        const float* t = dst; dst = (float*)src; src = t;
    }
    __syncthreads();                           // 7 levels (odd) -> result in B == src
    if (tid < 110) wsout[(size_t)blk * STRIDE + tid] = src[tid];
}

// ---------------------------------------------------------------------------
// K2: fold-then-apply, NO grid sync and no tree64 dispatch.
//  Prologue (per block): entry __syncthreads (free: nothing in flight) inits
//  an LDS flag; every wave issues its x-tile DMAs; wave 0 stages the 8 chunk
//  slots and folds 8->1 wave-synchronously (lgkm fences; ping-pong between
//  DISJOINT slot groups 0-7 -> 8-11 -> 0-1 -> 2 so compiler scheduling can't
//  interleave reads/writes of the same slots); waves 1-3 spin on the LDS flag
//  (block-local; their DMAs stay in flight). Composite sits in FC slot 2,
//  col-major: M[j][k] = s[k*10+j], bias = s[100+j].
//  Body: frozen round-10 barrier-free apply (DMA staging, 0 bank conflicts).
// ---------------------------------------------------------------------------
__global__ __launch_bounds__(256) void apply_fold(const float* __restrict__ x,
                                                  const float* __restrict__ chunks,
                                                  float* __restrict__ out,
                                                  int nq4) {
    __shared__ float4 lds4[4][WQ4];            // 20 KB
    __shared__ float FC[12 * STRIDE];          // 5.25 KB: slots 0-7 in, 8-11/0-1/2 tree
    __shared__ int fold_flag;
    const int tid  = threadIdx.x;
    const int w    = tid >> 6, lane = tid & 63;

    if (tid == 0) fold_flag = 0;
    __syncthreads();                           // free: no memory ops in flight yet

    const int q0 = blockIdx.x * TILE_Q4 + w * WQ4;   // this wave's float4 base
    const int rem = nq4 - q0;                  // wave 0 always has rem > 0
    if (w != 0 && rem <= 0) return;            // idle tail waves (no barriers below)

    const float4* __restrict__ xin = (const float4*)x + q0;
    float4* __restrict__ op = (float4*)out + q0;

    // issue this wave's 5 DMAs (in flight through the fold/spin)
    if (rem > 0) {
        #pragma unroll
        for (int i = 0; i < 5; ++i) {
            int q = i * 64 + lane;
            gload_lds16(xin + (q < rem ? q : 0), &lds4[w][i * 64]);
        }
    }

    if (w == 0) {
        // stage 8 chunk slots (8*112 floats = 224 float4) from L2
        const float4* c4 = (const float4*)chunks;
        float4* F4 = (float4*)FC;
        #pragma unroll
        for (int i = 0; i < 4; ++i) {
            int e = i * 64 + lane;
            if (e < NCH8 * (STRIDE / 4)) F4[e] = c4[e];
        }
        asm volatile("s_waitcnt vmcnt(0) lgkmcnt(0)" ::: "memory");
        __builtin_amdgcn_sched_barrier(0);

        const int c = lane >> 4, sub = lane & 15;
        // L1: slots 0-7 -> slots 8-11 (4 composes, lanes grouped by 16)
        if (sub <= DIM) compose_one(FC, FC + 8 * STRIDE, c, sub);
        asm volatile("s_waitcnt lgkmcnt(0)" ::: "memory");
        __builtin_amdgcn_sched_barrier(0);
        // L2: slots 8-11 -> slots 0-1
        if (c < 2 && sub <= DIM) compose_one(FC + 8 * STRIDE, FC, c, sub);
        asm volatile("s_waitcnt lgkmcnt(0)" ::: "memory");
        __builtin_amdgcn_sched_barrier(0);
        // L3: slots 0-1 -> slot 2
        if (c == 0 && sub <= DIM) compose_one(FC, FC + 2 * STRIDE, 0, sub);
        asm volatile("s_waitcnt lgkmcnt(0)" ::: "memory");
        __builtin_amdgcn_sched_barrier(0);
        if (lane == 0) *(volatile int*)&fold_flag = 1;
    } else {
        while (*(volatile int*)&fold_flag == 0) __builtin_amdgcn_s_sleep(2);
    }

    const float* s = FC + 2 * STRIDE;          // composite, col-major

    // ---- frozen apply body (round-10): wait DMA, redistribute, compute ----
    asm volatile("s_waitcnt vmcnt(0) lgkmcnt(0)" ::: "memory");
    __builtin_amdgcn_sched_barrier(0);

    float xv[20];                              // rows {2T, 2T+1}
    #pragma unroll
    for (int i = 0; i < 5; ++i) {
        float4 v = lds4[w][5 * lane + i];
        xv[4*i+0] = v.x; xv[4*i+1] = v.y; xv[4*i+2] = v.z; xv[4*i+3] = v.w;
    }

    float o[20];
    #pragma unroll
    for (int rr = 0; rr < 2; ++rr)
        #pragma unroll
        for (int j = 0; j < DIM; ++j) {
            float acc = s[100 + j];            // bias_j
            #pragma unroll
            for (int k = 0; k < DIM; ++k)
                acc += s[k * DIM + j] * xv[rr * DIM + k];   // M[j][k] col-major
            o[rr * DIM + j] = acc;
        }

    #pragma unroll
    for (int i = 0; i < 5; ++i)
        lds4[w][5 * lane + i] = make_float4(o[4*i+0], o[4*i+1], o[4*i+2], o[4*i+3]);

    asm volatile("s_waitcnt lgkmcnt(0)" ::: "memory");
    __builtin_amdgcn_sched_barrier(0);

    {
        float4 t0 = lds4[w][0 * 64 + lane];
        float4 t1 = lds4[w][1 * 64 + lane];
        float4 t2 = lds4[w][2 * 64 + lane];
        float4 t3 = lds4[w][3 * 64 + lane];
        float4 t4 = lds4[w][4 * 64 + lane];
        if (0 * 64 + lane < rem) op[0 * 64 + lane] = t0;
        if (1 * 64 + lane < rem) op[1 * 64 + lane] = t1;
        if (2 * 64 + lane < rem) op[2 * 64 + lane] = t2;
        if (3 * 64 + lane < rem) op[3 * 64 + lane] = t3;
        if (4 * 64 + lane < rem) op[4 * 64 + lane] = t4;
    }
}

extern "C" void kernel_launch(void* const* d_in, const int* in_sizes, int n_in,
                              void* d_out, int out_size, void* d_ws, size_t ws_size,
                              hipStream_t stream) {
    const float* x  = (const float*)d_in[0];   // [BATCH, 10]
    const float* Ws = (const float*)d_in[1];   // [1000, 10, 10]
    const float* bs = (const float*)d_in[2];   // [1000, 10]
    float* out = (float*)d_out;

    float* ws_chunks = (float*)d_ws;           // NCH8 * STRIDE floats, 16B aligned

    compose128<<<NCH8, 1024, 0, stream>>>(Ws, bs, ws_chunks);

    const int nq4 = in_sizes[0] / 4;           // in_sizes is in floats
    const int blocks = (nq4 + TILE_Q4 - 1) / TILE_Q4;
    apply_fold<<<blocks, 256, 0, stream>>>(x, ws_chunks, out, nq4);
}